// Round 4
// baseline (609.824 us; speedup 1.0000x reference)
//
#include <hip/hip_runtime.h>
#include <math.h>

#define EPS 1e-8f
#define UMAX 4   // 128-row tiles per block; grid = totalUnits/UMAX = 1024 -> 4 blocks/CU

typedef float nfloat4 __attribute__((ext_vector_type(4)));

__device__ __forceinline__ float softplus_f(float x) {
    return (x > 20.0f) ? x : log1pf(expf(x));
}
__device__ __forceinline__ float sigmoid_f(float x) {
    return 1.0f / (1.0f + expf(-x));
}

// Device-scope sense-reversing grid barrier (graph-capture-legal grid.sync).
// Release fence -> arrive; acquire-spin -> fence invalidates stale L1/L2 (G16).
// Bounded spin: a violated co-residency assumption yields a wrong answer fast,
// not a hang. Co-residency is resource-guaranteed: 4 blocks/CU needs 1024
// threads (cap 2048), ~20KB LDS (cap 40KB/block at 4/CU), VGPR<=128
// (enforced by __launch_bounds__(256,4)).
__device__ __forceinline__ void grid_barrier(unsigned* cnt, unsigned* gen, unsigned nb) {
    __syncthreads();
    if (threadIdx.x == 0) {
        __threadfence();
        unsigned g = __hip_atomic_load(gen, __ATOMIC_RELAXED, __HIP_MEMORY_SCOPE_AGENT);
        unsigned arrived = __hip_atomic_fetch_add(cnt, 1u, __ATOMIC_ACQ_REL, __HIP_MEMORY_SCOPE_AGENT);
        if (arrived == nb - 1u) {
            __hip_atomic_store(cnt, 0u, __ATOMIC_RELAXED, __HIP_MEMORY_SCOPE_AGENT);
            __hip_atomic_fetch_add(gen, 1u, __ATOMIC_RELEASE, __HIP_MEMORY_SCOPE_AGENT);
        } else {
            int tries = 0;
            while (__hip_atomic_load(gen, __ATOMIC_ACQUIRE, __HIP_MEMORY_SCOPE_AGENT) == g) {
                __builtin_amdgcn_s_sleep(2);
                if (++tries > (1 << 20)) break;   // safety valve
            }
        }
        __threadfence();
    }
    __syncthreads();
}

__global__ void init_barrier(unsigned* bar) { bar[0] = 0u; bar[1] = 0u; }

// ---- helpers (forceinline; register arrays passed by reference, static idx)
__device__ __forceinline__ void load_tile(float4 (&m4)[8],
    const float* __restrict__ memory, size_t rowbase, int rq, int lane)
{
    #pragma unroll
    for (int j = 0; j < 8; j++)
        m4[j] = ((const float4*)(memory + (rowbase + rq + 16 * j) * 64))[lane];
}

__device__ __forceinline__ void reduce_tile(const float4 (&m4)[8],
    const float4 (&k4)[4], const float (&beta_l)[4], const float (&kn_l)[4],
    float (*e_out)[128], int rq, int lane)
{
    #pragma unroll
    for (int j = 0; j < 8; j++) {
        float nsq = m4[j].x * m4[j].x + m4[j].y * m4[j].y
                  + m4[j].z * m4[j].z + m4[j].w * m4[j].w;
        float d[4];
        #pragma unroll
        for (int h = 0; h < 4; h++)
            d[h] = m4[j].x * k4[h].x + m4[j].y * k4[h].y
                 + m4[j].z * k4[h].z + m4[j].w * k4[h].w;
        #pragma unroll
        for (int m = 1; m < 16; m <<= 1) {
            nsq += __shfl_xor(nsq, m, 64);
            #pragma unroll
            for (int h = 0; h < 4; h++) d[h] += __shfl_xor(d[h], m, 64);
        }
        if (lane == 0) {
            float mn = sqrtf(nsq);
            int row = rq + 16 * j;
            #pragma unroll
            for (int h = 0; h < 4; h++) {
                float s = beta_l[h] * d[h] / (mn * kn_l[h] + EPS);
                e_out[h][row] = __expf(s - beta_l[h]);   // bounded (0,1]
            }
        }
    }
}

__device__ __forceinline__ void out_tile(const float4 (&m4)[8],
    const float4 (&e4)[4], const float4 (&w4)[4], const float (&invT_l)[4],
    const float (*ewp)[128], float* __restrict__ out, size_t rowbase,
    int rq, int lane)
{
    #pragma unroll
    for (int j = 0; j < 8; j++) {
        int row = rq + 16 * j;
        float4 pe = make_float4(1.f, 1.f, 1.f, 1.f);
        float4 up = make_float4(0.f, 0.f, 0.f, 0.f);
        #pragma unroll
        for (int h = 0; h < 4; h++) {
            float f = ewp[h][row] * invT_l[h];
            pe.x *= 1.0f - f * e4[h].x;  pe.y *= 1.0f - f * e4[h].y;
            pe.z *= 1.0f - f * e4[h].z;  pe.w *= 1.0f - f * e4[h].w;
            up.x += f * w4[h].x;  up.y += f * w4[h].y;
            up.z += f * w4[h].z;  up.w += f * w4[h].w;
        }
        nfloat4 o;
        o.x = m4[j].x * pe.x + up.x;
        o.y = m4[j].y * pe.y + up.y;
        o.z = m4[j].z * pe.z + up.z;
        o.w = m4[j].w * pe.w + up.w;
        __builtin_nontemporal_store(o, ((nfloat4*)(out + (rowbase + row) * 64)) + lane);
    }
}

// controls per b (792 floats): keys[4][64] | erase[4][64] | write[4][64]
//   | betas[4] | gates[4] | shifts[4][3] | gammas[4]
//
// One persistent kernel, 2 grid barriers (global softmax denom S, global
// sharpen normalizer T). Block owns UMAX=4 tiles of the SAME b (ntiles=64
// divisible by 4) -> all control prep hoisted to a single section.
// Phase 1/3: 2-deep double-buffered tile pipeline, no barriers in-loop.
// e / w^gamma persist in LDS across barriers; phase-3 memory re-read is
// same-block -> L2/L3-hot; out stores nontemporal.
__global__ __launch_bounds__(256, 4)
void fused_kernel(const float* __restrict__ memory,
                  const float* __restrict__ controls,
                  const float* __restrict__ prev,
                  float* __restrict__ out,
                  unsigned* __restrict__ bar,
                  float* __restrict__ S_part,
                  float* __restrict__ ebnd,
                  float* __restrict__ T_part,
                  int N, int B, unsigned nblocks)
{
    const int t = threadIdx.x;
    const int ntiles = N >> 7;
    const int blocksPerB = ntiles / UMAX;            // 16
    const int b = blockIdx.x / blocksPerB;
    const int chunk = blockIdx.x % blocksPerB;
    const int tile0 = chunk * UMAX;
    const int nbase0 = tile0 << 7;
    const float* c = controls + (size_t)b * 792;

    __shared__ __align__(16) float e_wp[UMAX][4][128];   // e, then w^gamma
    __shared__ __align__(16) float wiS[UMAX][4][130];    // w_interp + halo
    __shared__ __align__(16) float kk[256], es_s[256], wv_s[256];
    __shared__ float knorm_s[4], betas_s[4];
    __shared__ float scal_gate[4], scal_og[4], scal_s0[4], scal_s1[4], scal_s2[4], scal_gm[4];
    __shared__ float Ssh[4], invT_s[4];

    // ---------------- one-time prep (b is fixed for this block)
    {
        int h = t >> 6, w = t & 63;
        float kt = tanhf(c[h * 64 + w]);
        kk[h * 64 + w] = kt;
        float nsq = kt * kt;
        #pragma unroll
        for (int m = 1; m < 64; m <<= 1) nsq += __shfl_xor(nsq, m, 64);
        if (w == 0) knorm_s[h] = sqrtf(nsq);
        es_s[t] = sigmoid_f(c[256 + t]);
        wv_s[t] = tanhf(c[512 + t]);
        if (t < 4) {
            int h4 = t;
            betas_s[h4] = softplus_f(c[768 + h4]);
            float g = sigmoid_f(c[772 + h4]);
            scal_gate[h4] = g; scal_og[h4] = 1.0f - g;
            float r0 = c[776 + h4 * 3], r1 = c[776 + h4 * 3 + 1], r2 = c[776 + h4 * 3 + 2];
            float rmx = fmaxf(r0, fmaxf(r1, r2));
            float e0 = expf(r0 - rmx), e1 = expf(r1 - rmx), e2 = expf(r2 - rmx);
            float si = 1.0f / (e0 + e1 + e2);
            scal_s0[h4] = e0 * si; scal_s1[h4] = e1 * si; scal_s2[h4] = e2 * si;
            scal_gm[h4] = 1.0f + softplus_f(c[788 + h4]);
        }
    }
    __syncthreads();

    const int rq = t >> 4, lane = t & 15;
    const size_t rb0 = (size_t)b * N + nbase0;

    // ---------------- Phase 1: e = exp(beta*cos - beta), pipelined 2-deep
    {
        float4 k4[4];
        #pragma unroll
        for (int h = 0; h < 4; h++) k4[h] = ((const float4*)(kk + h * 64))[lane];
        float beta_l[4], kn_l[4];
        #pragma unroll
        for (int h = 0; h < 4; h++) { beta_l[h] = betas_s[h]; kn_l[h] = knorm_s[h]; }

        float4 mA[8], mB[8];
        load_tile(mA, memory, rb0, rq, lane);
        load_tile(mB, memory, rb0 + 128, rq, lane);
        reduce_tile(mA, k4, beta_l, kn_l, e_wp[0], rq, lane);
        load_tile(mA, memory, rb0 + 256, rq, lane);
        reduce_tile(mB, k4, beta_l, kn_l, e_wp[1], rq, lane);
        load_tile(mB, memory, rb0 + 384, rq, lane);
        reduce_tile(mA, k4, beta_l, kn_l, e_wp[2], rq, lane);
        reduce_tile(mB, k4, beta_l, kn_l, e_wp[3], rq, lane);
    }
    __syncthreads();

    // S partials (all 4 tiles at once) + tile-boundary e-values
    {
        int h = t >> 6, w = t & 63;
        float v = 0.0f;
        #pragma unroll
        for (int u = 0; u < UMAX; u++) v += e_wp[u][h][w] + e_wp[u][h][w + 64];
        #pragma unroll
        for (int m = 1; m < 64; m <<= 1) v += __shfl_xor(v, m, 64);
        if (w == 0) S_part[((size_t)b * 4 + h) * blocksPerB + chunk] = v;
    }
    if (t < 8 * UMAX) {
        int u = t >> 3, hh = (t >> 1) & 3, side = t & 1;
        size_t tt = (size_t)b * ntiles + tile0 + u;
        ebnd[tt * 8 + hh * 2 + side] = e_wp[u][hh][side ? 127 : 0];
    }

    grid_barrier(bar, bar + 1, nblocks);

    // ---------------- Phase 2: S reduce -> interp -> shift -> sharpen -> T partials
    {
        int h = t >> 6, w = t & 63;
        float v = 0.0f;
        for (int i = w; i < blocksPerB; i += 64)
            v += S_part[((size_t)b * 4 + h) * blocksPerB + i];
        #pragma unroll
        for (int m = 1; m < 64; m <<= 1) v += __shfl_xor(v, m, 64);
        if (w == 0) Ssh[h] = v;
    }

    const int h0 = t >> 7, row = t & 127, h1 = h0 + 2;
    float p0[UMAX], p1[UMAX];
    #pragma unroll
    for (int u = 0; u < UMAX; u++) {
        p0[u] = prev[((size_t)b * 4 + h0) * N + nbase0 + (u << 7) + row];
        p1[u] = prev[((size_t)b * 4 + h1) * N + nbase0 + (u << 7) + row];
    }
    float he = 0.f, hp = 0.f;
    int hu = 0, hh = 0, hside = 0;
    if (t < 8 * UMAX) {                          // circular halo loads (issue early)
        hu = t >> 3; hh = (t >> 1) & 3; hside = t & 1;
        int g = nbase0 + (hu << 7) + (hside ? 128 : -1);
        if (g < 0) g += N;
        if (g >= N) g -= N;
        int gt = g >> 7, gr = g & 127;
        he = ebnd[((size_t)b * ntiles + gt) * 8 + hh * 2 + (gr == 127 ? 1 : 0)];
        hp = prev[((size_t)b * 4 + hh) * N + g];
    }
    __syncthreads();                             // Ssh ready

    {
        float invS0 = 1.0f / Ssh[h0], invS1 = 1.0f / Ssh[h1];
        float g0 = scal_gate[h0], og0 = scal_og[h0];
        float g1 = scal_gate[h1], og1 = scal_og[h1];
        #pragma unroll
        for (int u = 0; u < UMAX; u++) {
            wiS[u][h0][row + 1] = g0 * e_wp[u][h0][row] * invS0 + og0 * p0[u];
            wiS[u][h1][row + 1] = g1 * e_wp[u][h1][row] * invS1 + og1 * p1[u];
        }
        if (t < 8 * UMAX)
            wiS[hu][hh][hside ? 129 : 0] =
                scal_gate[hh] * he * (1.0f / Ssh[hh]) + scal_og[hh] * hp;
    }
    __syncthreads();

    {
        float s00 = scal_s0[h0], s10 = scal_s1[h0], s20 = scal_s2[h0], gm0 = scal_gm[h0];
        float s01 = scal_s0[h1], s11 = scal_s1[h1], s21 = scal_s2[h1], gm1 = scal_gm[h1];
        #pragma unroll
        for (int u = 0; u < UMAX; u++) {
            float ws0 = s00 * wiS[u][h0][row] + s10 * wiS[u][h0][row + 1] + s20 * wiS[u][h0][row + 2];
            float ws1 = s01 * wiS[u][h1][row] + s11 * wiS[u][h1][row + 1] + s21 * wiS[u][h1][row + 2];
            // ws strictly > 0 (softmax>0, prev>=0, gate in (0,1)) -> fast pow
            e_wp[u][h0][row] = __expf(gm0 * __logf(ws0));
            e_wp[u][h1][row] = __expf(gm1 * __logf(ws1));
        }
    }
    __syncthreads();

    {
        int h = t >> 6, w = t & 63;
        float v = 0.0f;
        #pragma unroll
        for (int u = 0; u < UMAX; u++) v += e_wp[u][h][w] + e_wp[u][h][w + 64];
        #pragma unroll
        for (int m = 1; m < 64; m <<= 1) v += __shfl_xor(v, m, 64);
        if (w == 0) T_part[((size_t)b * 4 + h) * blocksPerB + chunk] = v;
    }

    grid_barrier(bar, bar + 1, nblocks);

    // ---------------- Phase 3: T reduce -> out, pipelined 2-deep
    {
        int h = t >> 6, w = t & 63;
        float v = 0.0f;
        for (int i = w; i < blocksPerB; i += 64)
            v += T_part[((size_t)b * 4 + h) * blocksPerB + i];
        #pragma unroll
        for (int m = 1; m < 64; m <<= 1) v += __shfl_xor(v, m, 64);
        if (w == 0) invT_s[h] = 1.0f / (v + EPS);
    }
    __syncthreads();

    {
        float4 e4[4], w4[4];
        #pragma unroll
        for (int h = 0; h < 4; h++) {
            e4[h] = ((const float4*)(es_s + h * 64))[lane];
            w4[h] = ((const float4*)(wv_s + h * 64))[lane];
        }
        float invT_l[4];
        #pragma unroll
        for (int h = 0; h < 4; h++) invT_l[h] = invT_s[h];

        float4 mA[8], mB[8];
        load_tile(mA, memory, rb0, rq, lane);
        load_tile(mB, memory, rb0 + 128, rq, lane);
        out_tile(mA, e4, w4, invT_l, e_wp[0], out, rb0, rq, lane);
        load_tile(mA, memory, rb0 + 256, rq, lane);
        out_tile(mB, e4, w4, invT_l, e_wp[1], out, rb0 + 128, rq, lane);
        load_tile(mB, memory, rb0 + 384, rq, lane);
        out_tile(mA, e4, w4, invT_l, e_wp[2], out, rb0 + 256, rq, lane);
        out_tile(mB, e4, w4, invT_l, e_wp[3], out, rb0 + 384, rq, lane);
    }
}

// -------------------------------------------------------------------------
extern "C" void kernel_launch(void* const* d_in, const int* in_sizes, int n_in,
                              void* d_out, int out_size, void* d_ws, size_t ws_size,
                              hipStream_t stream) {
    const float* memory   = (const float*)d_in[0];
    const float* controls = (const float*)d_in[1];
    const float* prev     = (const float*)d_in[2];
    float* out = (float*)d_out;

    int B = in_sizes[1] / 792;            // H*(3W+6) = 792
    int N = in_sizes[0] / (B * 64);       // W = 64
    int ntiles = N >> 7;                  // 64
    int blocksPerB = ntiles / UMAX;       // 16
    int totalUnits = B * ntiles;          // 4096
    unsigned nblocks = (unsigned)(totalUnits / UMAX);   // 1024 = 256 CU x 4

    // workspace: bar(2 u32, padded) | S_part | T_part | ebnd (all tiny)
    unsigned* bar = (unsigned*)d_ws;
    float* S_part = (float*)d_ws + 16;                       // B*4*blocksPerB
    float* T_part = S_part + (size_t)B * 4 * blocksPerB;     // B*4*blocksPerB
    float* ebnd   = T_part + (size_t)B * 4 * blocksPerB;     // totalUnits*8

    init_barrier<<<1, 1, 0, stream>>>(bar);
    fused_kernel<<<dim3(nblocks), dim3(256), 0, stream>>>(
        memory, controls, prev, out, bar, S_part, ebnd, T_part, N, B, nblocks);
}

// Round 5
// 265.702 us; speedup vs baseline: 2.2951x; 2.2951x over previous
//
#include <hip/hip_runtime.h>
#include <hip/hip_fp16.h>
#include <math.h>

#define EPS 1e-8f

typedef float nfloat4 __attribute__((ext_vector_type(4)));

__device__ __forceinline__ float softplus_f(float x) {
    return (x > 20.0f) ? x : log1pf(expf(x));
}
__device__ __forceinline__ float sigmoid_f(float x) {
    return 1.0f / (1.0f + expf(-x));
}

// controls per b (792 floats): keys[4][64] | erase[4][64] | write[4][64]
//   | betas[4] | gates[4] | shifts[4][3] | gammas[4]
//
// 3-kernel pipeline (fastest structure measured; no device barriers).
// Intermediates evals / wp stored as FP16: e in (0,1], w^gamma in [0,1]
// (prev in [0,1) -> w_interp <= 1), so fp16 is range-safe; S/T sums stay
// fp32 computed pre-rounding. Halves the 67 MB intermediate round-trip.

// -------------------------------------------------------------------------
// Kernel 1: e[b,h,n] = exp(beta_h*cos(key_h, mem[b,n]) - beta_h)
// (uniform -beta shift cancels in softmax; bounds e in (0,1] -> no max pass)
// + per-tile partial sums S_part[b,h,tile] (tile = 128 rows).
// block = 256 threads; 128 rows/block; grid = (N/128, B).
// -------------------------------------------------------------------------
__global__ __launch_bounds__(256)
void score_kernel(const float* __restrict__ memory,
                  const float* __restrict__ controls,
                  __half* __restrict__ evals,
                  float* __restrict__ S_part, int N)
{
    int b = blockIdx.y;
    int tile = blockIdx.x;
    int nbase = tile * 128;
    int t = threadIdx.x;
    int rq = t >> 4;      // 0..15
    int lane = t & 15;    // 0..15
    int ntiles = N >> 7;

    __shared__ float kk[256];
    __shared__ float betas_s[4], knorm_s[4];
    __shared__ float sc[4][128];

    const float* c = controls + (size_t)b * 792;

    // per-block key prep: wave h handles head h (h = t>>6, w = t&63)
    {
        int h = t >> 6, w = t & 63;
        float kt = tanhf(c[h * 64 + w]);
        kk[h * 64 + w] = kt;
        float nsq = kt * kt;
        #pragma unroll
        for (int m = 1; m < 64; m <<= 1) nsq += __shfl_xor(nsq, m, 64);
        if (w == 0) knorm_s[h] = sqrtf(nsq);
        if (t < 4)  betas_s[t] = softplus_f(c[768 + t]);
    }
    __syncthreads();

    float4 k4[4];
    #pragma unroll
    for (int h = 0; h < 4; h++) k4[h] = ((const float4*)(kk + h * 64))[lane];
    float beta_l[4], knorm_l[4];
    #pragma unroll
    for (int h = 0; h < 4; h++) { beta_l[h] = betas_s[h]; knorm_l[h] = knorm_s[h]; }

    // prefetch 8 rows (independent loads in flight)
    float4 m4[8];
    #pragma unroll
    for (int j = 0; j < 8; j++) {
        int n = nbase + rq + 16 * j;
        m4[j] = ((const float4*)(memory + ((size_t)b * N + n) * 64))[lane];
    }

    #pragma unroll
    for (int j = 0; j < 8; j++) {
        float nsq = m4[j].x * m4[j].x + m4[j].y * m4[j].y
                  + m4[j].z * m4[j].z + m4[j].w * m4[j].w;
        float d[4];
        #pragma unroll
        for (int h = 0; h < 4; h++) {
            d[h] = m4[j].x * k4[h].x + m4[j].y * k4[h].y
                 + m4[j].z * k4[h].z + m4[j].w * k4[h].w;
        }
        #pragma unroll
        for (int m = 1; m < 16; m <<= 1) {
            nsq += __shfl_xor(nsq, m, 64);
            #pragma unroll
            for (int h = 0; h < 4; h++) d[h] += __shfl_xor(d[h], m, 64);
        }
        if (lane == 0) {
            float mn = sqrtf(nsq);
            int row = rq + 16 * j;
            #pragma unroll
            for (int h = 0; h < 4; h++) {
                float s = beta_l[h] * d[h] / (mn * knorm_l[h] + EPS);
                sc[h][row] = __expf(s - beta_l[h]);   // bounded (0,1]
            }
        }
    }
    __syncthreads();

    // 512 half values out: each thread writes one __half2 (coalesced)
    {
        int h = t >> 6, i2 = t & 63;
        __half2 v = __floats2half2_rn(sc[h][2 * i2], sc[h][2 * i2 + 1]);
        ((__half2*)(evals + ((size_t)b * 4 + h) * N + nbase))[i2] = v;
    }

    // per-tile partial sum per head (fp32, pre-rounding): wave h sums head h
    {
        int h = t >> 6, w = t & 63;
        float v = sc[h][w] + sc[h][w + 64];
        #pragma unroll
        for (int m = 1; m < 64; m <<= 1) v += __shfl_xor(v, m, 64);
        if (w == 0) S_part[((size_t)b * 4 + h) * ntiles + tile] = v;
    }
}

// -------------------------------------------------------------------------
// Kernel 2: streaming interp -> circular 3-tap shift -> sharpen.
// Block = one 2048-element chunk of one (b,h); 256 thr x 8 elems.
// S = sum of 64 tile partials (one wave reduce). Own 8 w_interp in regs;
// 2 edge neighbors from LDS. Emits unnormalized w^gamma (fp16) + fp32
// per-chunk partials T_part; final 1/(T+EPS) folded into kernel 3.
// grid = B*4*(N/2048) = 1024.
// -------------------------------------------------------------------------
__global__ __launch_bounds__(256)
void shift_kernel(const __half* __restrict__ evals,
                  const float* __restrict__ prev,
                  const float* __restrict__ controls,
                  const float* __restrict__ S_part,
                  __half* __restrict__ wp,
                  float* __restrict__ T_part, int N)
{
    int CH = N >> 11;                    // 2048-element chunks per row
    int bh = blockIdx.x / CH;
    int chunk = blockIdx.x - bh * CH;
    int b = bh >> 2, h = bh & 3;
    int t = threadIdx.x;
    int ntiles = N >> 7;
    const float* c = controls + (size_t)b * 792;

    __shared__ float wl[2050];
    __shared__ float redm[4];
    __shared__ float Ssh;

    // S[b,h] = sum of tile partials (wave 0 only)
    if (t < 64) {
        float v = 0.0f;
        for (int i = t; i < ntiles; i += 64) v += S_part[(size_t)bh * ntiles + i];
        #pragma unroll
        for (int m = 1; m < 64; m <<= 1) v += __shfl_xor(v, m, 64);
        if (t == 0) Ssh = v;
    }

    float gate  = sigmoid_f(c[772 + h]);
    float r0 = c[776 + h * 3 + 0];
    float r1 = c[776 + h * 3 + 1];
    float r2 = c[776 + h * 3 + 2];
    float rmx = fmaxf(r0, fmaxf(r1, r2));
    float e0 = expf(r0 - rmx), e1 = expf(r1 - rmx), e2 = expf(r2 - rmx);
    float sinv = 1.0f / (e0 + e1 + e2);
    float s0 = e0 * sinv, s1 = e1 * sinv, s2 = e2 * sinv;
    float gamma = 1.0f + softplus_f(c[788 + h]);

    const __half* erow = evals + (size_t)bh * N;
    const float* prow  = prev  + (size_t)bh * N;
    int base = chunk << 11;
    int li = t << 3;                     // local index of first owned element

    // 8 halves in one 16B load
    float4 eraw = ((const float4*)(erow + base))[t];
    const __half2* eh2 = (const __half2*)&eraw;
    float2 e01 = __half22float2(eh2[0]);
    float2 e23 = __half22float2(eh2[1]);
    float2 e45 = __half22float2(eh2[2]);
    float2 e67 = __half22float2(eh2[3]);

    float4 pa = ((const float4*)(prow + base))[2 * t];
    float4 pb = ((const float4*)(prow + base))[2 * t + 1];

    __syncthreads();                     // Ssh ready
    float invS = 1.0f / Ssh;
    float og = 1.0f - gate;

    float w[8];
    w[0] = gate * e01.x * invS + og * pa.x;
    w[1] = gate * e01.y * invS + og * pa.y;
    w[2] = gate * e23.x * invS + og * pa.z;
    w[3] = gate * e23.y * invS + og * pa.w;
    w[4] = gate * e45.x * invS + og * pb.x;
    w[5] = gate * e45.y * invS + og * pb.y;
    w[6] = gate * e67.x * invS + og * pb.z;
    w[7] = gate * e67.y * invS + og * pb.w;

    // wl[1+j] = w_interp[base+j]; wl[0]/wl[2049] = circular halo
    #pragma unroll
    for (int k = 0; k < 8; k++) wl[1 + li + k] = w[k];
    if (t == 0) {
        int g = base - 1; if (g < 0) g += N;
        wl[0] = gate * __half2float(erow[g]) * invS + og * prow[g];
    }
    if (t == 255) {
        int g = base + 2048; if (g >= N) g -= N;
        wl[2049] = gate * __half2float(erow[g]) * invS + og * prow[g];
    }
    __syncthreads();

    float nb[10];
    nb[0] = wl[li];                      // w_interp[base+li-1]
    #pragma unroll
    for (int k = 0; k < 8; k++) nb[k + 1] = w[k];
    nb[9] = wl[li + 9];                  // w_interp[base+li+8]

    float o[8];
    float acc = 0.0f;
    #pragma unroll
    for (int k = 0; k < 8; k++) {
        float ws = s0 * nb[k] + s1 * nb[k + 1] + s2 * nb[k + 2];
        // ws strictly > 0 (softmax>0, prev>=0, gate in (0,1)) -> fast pow
        float v = __expf(gamma * __logf(ws));
        o[k] = v; acc += v;
    }

    #pragma unroll
    for (int m = 1; m < 64; m <<= 1) acc += __shfl_xor(acc, m, 64);
    if ((t & 63) == 0) redm[t >> 6] = acc;
    __syncthreads();
    if (t == 0) T_part[(size_t)bh * CH + chunk] = redm[0] + redm[1] + redm[2] + redm[3];

    // 8 values -> 4 half2 -> one 16B store (w^gamma <= 1, fp16-safe)
    float4 oraw;
    __half2* oh2 = (__half2*)&oraw;
    oh2[0] = __floats2half2_rn(o[0], o[1]);
    oh2[1] = __floats2half2_rn(o[2], o[3]);
    oh2[2] = __floats2half2_rn(o[4], o[5]);
    oh2[3] = __floats2half2_rn(o[6], o[7]);
    ((float4*)(wp + (size_t)bh * N + base))[t] = oraw;
}

// -------------------------------------------------------------------------
// Kernel 3: out[b,n,w] = mem * prod_h(1 - wd[h,n]*erase[h,w]) + sum_h wd*write
// wd = fp16(w^gamma) * 1/(T+EPS): normalization folded into wd_s staging.
// block = 256 threads; 128 rows/block; 8 rows/thread.
// Non-temporal out stores keep L3 for memory[] (L3-hot from kernel 1).
// grid = B * N/128.
// -------------------------------------------------------------------------
__global__ __launch_bounds__(256)
void output_kernel(const float* __restrict__ memory,
                   const __half* __restrict__ wdist,
                   const float* __restrict__ T_part,
                   const float* __restrict__ controls,
                   float* __restrict__ out, int N)
{
    int t = threadIdx.x;
    int blocksPerB = N >> 7;
    int b = blockIdx.x / blocksPerB;
    int nbase = (blockIdx.x % blocksPerB) << 7;
    int CH = N >> 11;

    __shared__ float es[256], wv[256], wd_s[512], invT_s[4];
    const float* c = controls + (size_t)b * 792;
    if (t < 4) {
        float s = 0.0f;
        for (int cc = 0; cc < CH; cc++) s += T_part[((size_t)b * 4 + t) * CH + cc];
        invT_s[t] = 1.0f / (s + EPS);
    }
    es[t] = sigmoid_f(c[256 + t]);
    wv[t] = tanhf(c[512 + t]);
    __syncthreads();
    // 512 halves staged: each thread one __half2, normalize folded in
    {
        int h = t >> 6, i2 = t & 63;
        __half2 v = ((const __half2*)(wdist + ((size_t)b * 4 + h) * N + nbase))[i2];
        float2 f = __half22float2(v);
        wd_s[h * 128 + 2 * i2]     = f.x * invT_s[h];
        wd_s[h * 128 + 2 * i2 + 1] = f.y * invT_s[h];
    }
    __syncthreads();

    int rq = t >> 4, lane = t & 15;

    float4 e4[4], w4[4];
    #pragma unroll
    for (int h = 0; h < 4; h++) {
        e4[h] = ((const float4*)(es + h * 64))[lane];
        w4[h] = ((const float4*)(wv + h * 64))[lane];
    }

    float4 m4[8];
    #pragma unroll
    for (int j = 0; j < 8; j++) {
        int n = nbase + rq + 16 * j;
        m4[j] = ((const float4*)(memory + ((size_t)b * N + n) * 64))[lane];
    }

    #pragma unroll
    for (int j = 0; j < 8; j++) {
        int row = rq + 16 * j;
        int n = nbase + row;
        float4 pe = make_float4(1.f, 1.f, 1.f, 1.f);
        float4 up = make_float4(0.f, 0.f, 0.f, 0.f);
        #pragma unroll
        for (int h = 0; h < 4; h++) {
            float f = wd_s[h * 128 + row];
            pe.x *= 1.0f - f * e4[h].x;  pe.y *= 1.0f - f * e4[h].y;
            pe.z *= 1.0f - f * e4[h].z;  pe.w *= 1.0f - f * e4[h].w;
            up.x += f * w4[h].x;  up.y += f * w4[h].y;
            up.z += f * w4[h].z;  up.w += f * w4[h].w;
        }
        nfloat4 o;
        o.x = m4[j].x * pe.x + up.x;
        o.y = m4[j].y * pe.y + up.y;
        o.z = m4[j].z * pe.z + up.z;
        o.w = m4[j].w * pe.w + up.w;
        nfloat4* op = ((nfloat4*)(out + ((size_t)b * N + n) * 64)) + lane;
        __builtin_nontemporal_store(o, op);
    }
}

// -------------------------------------------------------------------------
extern "C" void kernel_launch(void* const* d_in, const int* in_sizes, int n_in,
                              void* d_out, int out_size, void* d_ws, size_t ws_size,
                              hipStream_t stream) {
    const float* memory   = (const float*)d_in[0];
    const float* controls = (const float*)d_in[1];
    const float* prev     = (const float*)d_in[2];
    float* out = (float*)d_out;

    int B = in_sizes[1] / 792;            // H*(3W+6) = 792
    int N = in_sizes[0] / (B * 64);       // W = 64
    int ntiles = N >> 7;                  // 128-row tiles (64)
    int CH = N >> 11;                     // 2048-elem chunks (4)

    // workspace layout: evals(fp16) | wp(fp16) | S_part(f32) | T_part(f32)
    __half* evals = (__half*)d_ws;                          // B*4*N halves
    __half* wp    = evals + (size_t)B * 4 * N;              // B*4*N halves
    float* S_part = (float*)(wp + (size_t)B * 4 * N);       // B*4*ntiles
    float* T_part = S_part + (size_t)B * 4 * ntiles;        // B*4*CH

    score_kernel<<<dim3(ntiles, B), 256, 0, stream>>>(memory, controls, evals, S_part, N);
    shift_kernel<<<B * 4 * CH, 256, 0, stream>>>(evals, prev, controls, S_part, wp, T_part, N);
    output_kernel<<<B * ntiles, 256, 0, stream>>>(memory, wp, T_part, controls, out, N);
}

// Round 6
// 261.348 us; speedup vs baseline: 2.3334x; 1.0167x over previous
//
#include <hip/hip_runtime.h>
#include <hip/hip_fp16.h>
#include <math.h>

#define EPS 1e-8f

typedef float nfloat4 __attribute__((ext_vector_type(4)));

__device__ __forceinline__ float softplus_f(float x) {
    return (x > 20.0f) ? x : log1pf(expf(x));
}
__device__ __forceinline__ float sigmoid_f(float x) {
    return 1.0f / (1.0f + expf(-x));
}

// controls per b (792 floats): keys[4][64] | erase[4][64] | write[4][64]
//   | betas[4] | gates[4] | shifts[4][3] | gammas[4]
//
// 3-kernel pipeline. Intermediates fp16 (L3-hot; range-safe: e in (0,1],
// w^gamma in [0,1]); S/T sums fp32 pre-rounding.

// -------------------------------------------------------------------------
// Kernel 1: e[b,h,n] = exp(beta_h*cos(key_h, mem[b,n]) - beta_h)
// + per-tile partial sums S_part[b,h,tile] (tile = 128 rows).
//
// 4-lanes-per-row layout: lane owns a quarter-row (16 floats), keys for its
// quarter live in registers, reduction = 2 shuffle rounds (vs 4 at 16-lane):
// 20 DS-class insts/thread total vs 160 -> K1 stops being DS-pipe-bound.
// block = 256 threads; 128 rows/block; grid = (N/128, B).
// -------------------------------------------------------------------------
__global__ __launch_bounds__(256)
void score_kernel(const float* __restrict__ memory,
                  const float* __restrict__ controls,
                  __half* __restrict__ evals,
                  float* __restrict__ S_part, int N)
{
    int b = blockIdx.y;
    int tile = blockIdx.x;
    int nbase = tile * 128;
    int t = threadIdx.x;
    int ntiles = N >> 7;

    __shared__ float kk[256];
    __shared__ float betas_s[4], knorm_s[4];
    __shared__ float sc[4][128];

    const float* c = controls + (size_t)b * 792;

    // per-block key prep: wave h handles head h (h = t>>6, w = t&63)
    {
        int h = t >> 6, w = t & 63;
        float kt = tanhf(c[h * 64 + w]);
        kk[h * 64 + w] = kt;
        float nsq = kt * kt;
        #pragma unroll
        for (int m = 1; m < 64; m <<= 1) nsq += __shfl_xor(nsq, m, 64);
        if (w == 0) knorm_s[h] = sqrtf(nsq);
        if (t < 4)  betas_s[t] = softplus_f(c[768 + t]);
    }
    __syncthreads();

    const int qr = t & 3;         // quarter within row
    const int rowi = t >> 2;      // 0..63 ; rows rowi and rowi+64

    // keys for this thread's quarter: k[h][qr*16 .. qr*16+15] in registers
    float4 kq[4][4];
    #pragma unroll
    for (int h = 0; h < 4; h++)
        #pragma unroll
        for (int q = 0; q < 4; q++)
            kq[h][q] = ((const float4*)(kk + h * 64 + qr * 16))[q];

    float beta_l[4], knorm_l[4];
    #pragma unroll
    for (int h = 0; h < 4; h++) { beta_l[h] = betas_s[h]; knorm_l[h] = knorm_s[h]; }

    // issue all 8 quarter-row loads up front (lane l inst q -> byte 64*l+16*q
    // within the 16KB half-tile: L1 absorbs the stride-64 interleave)
    const float* r0p = memory + ((size_t)b * N + nbase + rowi) * 64 + qr * 16;
    const float* r1p = r0p + (size_t)64 * 64;   // row rowi+64
    float4 ma[4], mb[4];
    #pragma unroll
    for (int q = 0; q < 4; q++) ma[q] = ((const float4*)r0p)[q];
    #pragma unroll
    for (int q = 0; q < 4; q++) mb[q] = ((const float4*)r1p)[q];

    #pragma unroll
    for (int jj = 0; jj < 2; jj++) {
        const float4* mq = (jj == 0) ? ma : mb;
        int row = rowi + 64 * jj;
        float nsq = 0.0f;
        float d[4] = {0.f, 0.f, 0.f, 0.f};
        #pragma unroll
        for (int q = 0; q < 4; q++) {
            float4 m4 = mq[q];
            nsq += m4.x * m4.x + m4.y * m4.y + m4.z * m4.z + m4.w * m4.w;
            #pragma unroll
            for (int h = 0; h < 4; h++) {
                d[h] += m4.x * kq[h][q].x + m4.y * kq[h][q].y
                      + m4.z * kq[h][q].z + m4.w * kq[h][q].w;
            }
        }
        // 4-lane segmented reduce: 2 rounds only
        #pragma unroll
        for (int m = 1; m < 4; m <<= 1) {
            nsq += __shfl_xor(nsq, m, 64);
            #pragma unroll
            for (int h = 0; h < 4; h++) d[h] += __shfl_xor(d[h], m, 64);
        }
        if (qr == 0) {
            float mn = sqrtf(nsq);
            #pragma unroll
            for (int h = 0; h < 4; h++) {
                float s = beta_l[h] * d[h] / (mn * knorm_l[h] + EPS);
                sc[h][row] = __expf(s - beta_l[h]);   // bounded (0,1]
            }
        }
    }
    __syncthreads();

    // 512 half values out: each thread writes one __half2 (coalesced)
    {
        int h = t >> 6, i2 = t & 63;
        __half2 v = __floats2half2_rn(sc[h][2 * i2], sc[h][2 * i2 + 1]);
        ((__half2*)(evals + ((size_t)b * 4 + h) * N + nbase))[i2] = v;
    }

    // per-tile partial sum per head (fp32, pre-rounding): wave h sums head h
    {
        int h = t >> 6, w = t & 63;
        float v = sc[h][w] + sc[h][w + 64];
        #pragma unroll
        for (int m = 1; m < 64; m <<= 1) v += __shfl_xor(v, m, 64);
        if (w == 0) S_part[((size_t)b * 4 + h) * ntiles + tile] = v;
    }
}

// -------------------------------------------------------------------------
// Kernel 2: streaming interp -> circular 3-tap shift -> sharpen.
// Block = one 2048-element chunk of one (b,h); 256 thr x 8 elems.
// Emits unnormalized w^gamma (fp16) + fp32 per-chunk partials T_part;
// final 1/(T+EPS) folded into kernel 3. grid = B*4*(N/2048) = 1024.
// -------------------------------------------------------------------------
__global__ __launch_bounds__(256)
void shift_kernel(const __half* __restrict__ evals,
                  const float* __restrict__ prev,
                  const float* __restrict__ controls,
                  const float* __restrict__ S_part,
                  __half* __restrict__ wp,
                  float* __restrict__ T_part, int N)
{
    int CH = N >> 11;                    // 2048-element chunks per row
    int bh = blockIdx.x / CH;
    int chunk = blockIdx.x - bh * CH;
    int b = bh >> 2, h = bh & 3;
    int t = threadIdx.x;
    int ntiles = N >> 7;
    const float* c = controls + (size_t)b * 792;

    __shared__ float wl[2050];
    __shared__ float redm[4];
    __shared__ float Ssh;

    // S[b,h] = sum of tile partials (wave 0 only)
    if (t < 64) {
        float v = 0.0f;
        for (int i = t; i < ntiles; i += 64) v += S_part[(size_t)bh * ntiles + i];
        #pragma unroll
        for (int m = 1; m < 64; m <<= 1) v += __shfl_xor(v, m, 64);
        if (t == 0) Ssh = v;
    }

    float gate  = sigmoid_f(c[772 + h]);
    float r0 = c[776 + h * 3 + 0];
    float r1 = c[776 + h * 3 + 1];
    float r2 = c[776 + h * 3 + 2];
    float rmx = fmaxf(r0, fmaxf(r1, r2));
    float e0 = expf(r0 - rmx), e1 = expf(r1 - rmx), e2 = expf(r2 - rmx);
    float sinv = 1.0f / (e0 + e1 + e2);
    float s0 = e0 * sinv, s1 = e1 * sinv, s2 = e2 * sinv;
    float gamma = 1.0f + softplus_f(c[788 + h]);

    const __half* erow = evals + (size_t)bh * N;
    const float* prow  = prev  + (size_t)bh * N;
    int base = chunk << 11;
    int li = t << 3;                     // local index of first owned element

    // 8 halves in one 16B load
    float4 eraw = ((const float4*)(erow + base))[t];
    const __half2* eh2 = (const __half2*)&eraw;
    float2 e01 = __half22float2(eh2[0]);
    float2 e23 = __half22float2(eh2[1]);
    float2 e45 = __half22float2(eh2[2]);
    float2 e67 = __half22float2(eh2[3]);

    float4 pa = ((const float4*)(prow + base))[2 * t];
    float4 pb = ((const float4*)(prow + base))[2 * t + 1];

    __syncthreads();                     // Ssh ready
    float invS = 1.0f / Ssh;
    float og = 1.0f - gate;

    float w[8];
    w[0] = gate * e01.x * invS + og * pa.x;
    w[1] = gate * e01.y * invS + og * pa.y;
    w[2] = gate * e23.x * invS + og * pa.z;
    w[3] = gate * e23.y * invS + og * pa.w;
    w[4] = gate * e45.x * invS + og * pb.x;
    w[5] = gate * e45.y * invS + og * pb.y;
    w[6] = gate * e67.x * invS + og * pb.z;
    w[7] = gate * e67.y * invS + og * pb.w;

    // wl[1+j] = w_interp[base+j]; wl[0]/wl[2049] = circular halo
    #pragma unroll
    for (int k = 0; k < 8; k++) wl[1 + li + k] = w[k];
    if (t == 0) {
        int g = base - 1; if (g < 0) g += N;
        wl[0] = gate * __half2float(erow[g]) * invS + og * prow[g];
    }
    if (t == 255) {
        int g = base + 2048; if (g >= N) g -= N;
        wl[2049] = gate * __half2float(erow[g]) * invS + og * prow[g];
    }
    __syncthreads();

    float nb[10];
    nb[0] = wl[li];                      // w_interp[base+li-1]
    #pragma unroll
    for (int k = 0; k < 8; k++) nb[k + 1] = w[k];
    nb[9] = wl[li + 9];                  // w_interp[base+li+8]

    float o[8];
    float acc = 0.0f;
    #pragma unroll
    for (int k = 0; k < 8; k++) {
        float ws = s0 * nb[k] + s1 * nb[k + 1] + s2 * nb[k + 2];
        // ws strictly > 0 (softmax>0, prev>=0, gate in (0,1)) -> fast pow
        float v = __expf(gamma * __logf(ws));
        o[k] = v; acc += v;
    }

    #pragma unroll
    for (int m = 1; m < 64; m <<= 1) acc += __shfl_xor(acc, m, 64);
    if ((t & 63) == 0) redm[t >> 6] = acc;
    __syncthreads();
    if (t == 0) T_part[(size_t)bh * CH + chunk] = redm[0] + redm[1] + redm[2] + redm[3];

    // 8 values -> 4 half2 -> one 16B store (w^gamma <= 1, fp16-safe)
    float4 oraw;
    __half2* oh2 = (__half2*)&oraw;
    oh2[0] = __floats2half2_rn(o[0], o[1]);
    oh2[1] = __floats2half2_rn(o[2], o[3]);
    oh2[2] = __floats2half2_rn(o[4], o[5]);
    oh2[3] = __floats2half2_rn(o[6], o[7]);
    ((float4*)(wp + (size_t)bh * N + base))[t] = oraw;
}

// -------------------------------------------------------------------------
// Kernel 3: out[b,n,w] = mem * prod_h(1 - wd[h,n]*erase[h,w]) + sum_h wd*write
// wd = fp16(w^gamma) * 1/(T+EPS): normalization folded into wd_s staging.
// block = 256 threads; 128 rows/block; 8 rows/thread; NT out stores.
// grid = B * N/128.
// -------------------------------------------------------------------------
__global__ __launch_bounds__(256)
void output_kernel(const float* __restrict__ memory,
                   const __half* __restrict__ wdist,
                   const float* __restrict__ T_part,
                   const float* __restrict__ controls,
                   float* __restrict__ out, int N)
{
    int t = threadIdx.x;
    int blocksPerB = N >> 7;
    int b = blockIdx.x / blocksPerB;
    int nbase = (blockIdx.x % blocksPerB) << 7;
    int CH = N >> 11;

    __shared__ float es[256], wv[256], wd_s[512], invT_s[4];
    const float* c = controls + (size_t)b * 792;
    if (t < 4) {
        float s = 0.0f;
        for (int cc = 0; cc < CH; cc++) s += T_part[((size_t)b * 4 + t) * CH + cc];
        invT_s[t] = 1.0f / (s + EPS);
    }
    es[t] = sigmoid_f(c[256 + t]);
    wv[t] = tanhf(c[512 + t]);
    __syncthreads();
    // 512 halves staged: each thread one __half2, normalize folded in
    {
        int h = t >> 6, i2 = t & 63;
        __half2 v = ((const __half2*)(wdist + ((size_t)b * 4 + h) * N + nbase))[i2];
        float2 f = __half22float2(v);
        wd_s[h * 128 + 2 * i2]     = f.x * invT_s[h];
        wd_s[h * 128 + 2 * i2 + 1] = f.y * invT_s[h];
    }
    __syncthreads();

    int rq = t >> 4, lane = t & 15;

    float4 e4[4], w4[4];
    #pragma unroll
    for (int h = 0; h < 4; h++) {
        e4[h] = ((const float4*)(es + h * 64))[lane];
        w4[h] = ((const float4*)(wv + h * 64))[lane];
    }

    float4 m4[8];
    #pragma unroll
    for (int j = 0; j < 8; j++) {
        int n = nbase + rq + 16 * j;
        m4[j] = ((const float4*)(memory + ((size_t)b * N + n) * 64))[lane];
    }

    #pragma unroll
    for (int j = 0; j < 8; j++) {
        int row = rq + 16 * j;
        int n = nbase + row;
        float4 pe = make_float4(1.f, 1.f, 1.f, 1.f);
        float4 up = make_float4(0.f, 0.f, 0.f, 0.f);
        #pragma unroll
        for (int h = 0; h < 4; h++) {
            float f = wd_s[h * 128 + row];
            pe.x *= 1.0f - f * e4[h].x;  pe.y *= 1.0f - f * e4[h].y;
            pe.z *= 1.0f - f * e4[h].z;  pe.w *= 1.0f - f * e4[h].w;
            up.x += f * w4[h].x;  up.y += f * w4[h].y;
            up.z += f * w4[h].z;  up.w += f * w4[h].w;
        }
        nfloat4 o;
        o.x = m4[j].x * pe.x + up.x;
        o.y = m4[j].y * pe.y + up.y;
        o.z = m4[j].z * pe.z + up.z;
        o.w = m4[j].w * pe.w + up.w;
        nfloat4* op = ((nfloat4*)(out + ((size_t)b * N + n) * 64)) + lane;
        __builtin_nontemporal_store(o, op);
    }
}

// -------------------------------------------------------------------------
extern "C" void kernel_launch(void* const* d_in, const int* in_sizes, int n_in,
                              void* d_out, int out_size, void* d_ws, size_t ws_size,
                              hipStream_t stream) {
    const float* memory   = (const float*)d_in[0];
    const float* controls = (const float*)d_in[1];
    const float* prev     = (const float*)d_in[2];
    float* out = (float*)d_out;

    int B = in_sizes[1] / 792;            // H*(3W+6) = 792
    int N = in_sizes[0] / (B * 64);       // W = 64
    int ntiles = N >> 7;                  // 128-row tiles (64)
    int CH = N >> 11;                     // 2048-elem chunks (4)

    // workspace layout: evals(fp16) | wp(fp16) | S_part(f32) | T_part(f32)
    __half* evals = (__half*)d_ws;                          // B*4*N halves
    __half* wp    = evals + (size_t)B * 4 * N;              // B*4*N halves
    float* S_part = (float*)(wp + (size_t)B * 4 * N);       // B*4*ntiles
    float* T_part = S_part + (size_t)B * 4 * ntiles;        // B*4*CH

    score_kernel<<<dim3(ntiles, B), 256, 0, stream>>>(memory, controls, evals, S_part, N);
    shift_kernel<<<B * 4 * CH, 256, 0, stream>>>(evals, prev, controls, S_part, wp, T_part, N);
    output_kernel<<<B * ntiles, 256, 0, stream>>>(memory, wp, T_part, controls, out, N);
}